// Round 14
// baseline (215.908 us; speedup 1.0000x reference)
//
#include <hip/hip_runtime.h>

typedef __bf16 bf16x8 __attribute__((ext_vector_type(8)));
typedef float f32x4 __attribute__((ext_vector_type(4)));

__device__ __forceinline__ unsigned short f2bf(float f) {
    unsigned int u = __builtin_bit_cast(unsigned int, f);
    u += 0x7fff + ((u >> 16) & 1);   // round-to-nearest-even (finite inputs)
    return (unsigned short)(u >> 16);
}

// ---------------------------------------------------------------------------
// Stage a 128x64 A-tile + 128x64 B-tile (bf16) into lds[0..8191]/[8192..16383]
// via global_load_lds. Source chunk pre-swizzled c^(row&7); read side applies
// the same XOR (both-sides-or-neither, rule #21). 256 threads x 4 iters.
// ---------------------------------------------------------------------------
__device__ __forceinline__ void stage_pair(
    const unsigned short* __restrict__ Ap, int lda,
    const unsigned short* __restrict__ Bp, int ldb,
    unsigned short* lds, int k0, int tid)
{
#pragma unroll
    for (int it = 0; it < 4; ++it) {
        int li = it * 256 + tid;          // 0..1023: row = li>>3, chunk = li&7
        int row = li >> 3;
        int sc = ((li & 7) ^ (row & 7)) * 8;
        __builtin_amdgcn_global_load_lds(
            (const __attribute__((address_space(1))) void*)(Ap + (long)row * lda + k0 + sc),
            (__attribute__((address_space(3))) void*)&lds[li * 8], 16, 0, 0);
        __builtin_amdgcn_global_load_lds(
            (const __attribute__((address_space(1))) void*)(Bp + (long)row * ldb + k0 + sc),
            (__attribute__((address_space(3))) void*)&lds[8192 + li * 8], 16, 0, 0);
    }
}

// Stage just one 128x64 A-tile (8192 el) into buf.
__device__ __forceinline__ void stage_one(
    const unsigned short* __restrict__ Ap, int lda,
    unsigned short* buf, int k0, int tid)
{
#pragma unroll
    for (int it = 0; it < 4; ++it) {
        int li = it * 256 + tid;
        int row = li >> 3;
        int sc = ((li & 7) ^ (row & 7)) * 8;
        __builtin_amdgcn_global_load_lds(
            (const __attribute__((address_space(1))) void*)(Ap + (long)row * lda + k0 + sc),
            (__attribute__((address_space(3))) void*)&buf[li * 8], 16, 0, 0);
    }
}

// ---------------------------------------------------------------------------
// One 64-deep K-step from a staged tile pair (swizzled read).
// 4 waves, wave-tile 64x64, acc[4][4]. D row <- A-tile row, D col <- B row.
// ---------------------------------------------------------------------------
__device__ __forceinline__ void compute_tile(
    const unsigned short* lds, int lane, int wm, int wn, f32x4 (&acc)[4][4])
{
#pragma unroll
    for (int kk = 0; kk < 2; ++kk) {
        const int cl = kk * 4 + (lane >> 4);
        bf16x8 af[4], bfr[4];
#pragma unroll
        for (int m = 0; m < 4; ++m) {
            int row = wm + m * 16 + (lane & 15);
            af[m] = *(const bf16x8*)&lds[row * 64 + ((cl ^ (row & 7)) * 8)];
        }
#pragma unroll
        for (int n = 0; n < 4; ++n) {
            int row = wn + n * 16 + (lane & 15);
            bfr[n] = *(const bf16x8*)&lds[8192 + row * 64 + ((cl ^ (row & 7)) * 8)];
        }
#pragma unroll
        for (int m = 0; m < 4; ++m)
#pragma unroll
            for (int n = 0; n < 4; ++n)
                acc[m][n] = __builtin_amdgcn_mfma_f32_16x16x32_bf16(af[m], bfr[n], acc[m][n], 0, 0, 0);
    }
}

// Like compute_tile but B-fragments come from a [128][256] swizzled LDS Sc
// buffer at K-offset k0 (A from a staged 128x64 buffer).
__device__ __forceinline__ void compute_bsc(
    const unsigned short* bufA, const unsigned short* Sc, int k0,
    int lane, int wm, int wn, f32x4 (&acc)[4][4])
{
#pragma unroll
    for (int kk = 0; kk < 2; ++kk) {
        const int cl = kk * 4 + (lane >> 4);
        bf16x8 af[4], bfr[4];
#pragma unroll
        for (int m = 0; m < 4; ++m) {
            int row = wm + m * 16 + (lane & 15);
            af[m] = *(const bf16x8*)&bufA[row * 64 + ((cl ^ (row & 7)) * 8)];
        }
#pragma unroll
        for (int n = 0; n < 4; ++n) {
            int row = wn + n * 16 + (lane & 15);
            bfr[n] = *(const bf16x8*)&Sc[row * 256 + k0 + ((cl ^ (row & 7)) * 8)];
        }
#pragma unroll
        for (int m = 0; m < 4; ++m)
#pragma unroll
            for (int n = 0; n < 4; ++n)
                acc[m][n] = __builtin_amdgcn_mfma_f32_16x16x32_bf16(af[m], bfr[n], acc[m][n], 0, 0, 0);
    }
}

// ---------------------------------------------------------------------------
// Weights only: Wcat[g][q][512] = [W_gx | W_gh] rows (bf16) and Woc bf16.
// ---------------------------------------------------------------------------
__global__ __launch_bounds__(256)
void cvt_w(const float* __restrict__ fx, const float* __restrict__ ix,
           const float* __restrict__ ox, const float* __restrict__ gx,
           const float* __restrict__ fh, const float* __restrict__ ih,
           const float* __restrict__ oh, const float* __restrict__ gh,
           const float* __restrict__ oc,
           unsigned short* __restrict__ Wcat, unsigned short* __restrict__ Wocb)
{
    int idx = blockIdx.x * 256 + threadIdx.x;
    if (idx < 524288) {
        int g = idx >> 17;
        int rem = idx & 131071;
        int q = rem >> 9;
        int j = rem & 511;
        const float* xs = (g == 0) ? fx : (g == 1) ? ix : (g == 2) ? ox : gx;
        const float* hs = (g == 0) ? fh : (g == 1) ? ih : (g == 2) ? oh : gh;
        float v = (j < 256) ? xs[q * 256 + j] : hs[q * 256 + (j - 256)];
        Wcat[idx] = f2bf(v);
    } else if (idx < 589824) {
        int k = idx - 524288;
        Wocb[k] = f2bf(oc[k]);
    }
}

// ---------------------------------------------------------------------------
// Stage 1, flipped NT with FUSED fp32->bf16 on the B-operand (X/H read
// directly; no XHb pass):
//   S_T[g][b][q][hf*256+i] = sum_j Wcat[g][q][hf*256+j] * M_hf[b][i][j]
// A (Wcat bf16) via global_load_lds; B (M fp32) via reg-prefetch + f2bf +
// swizzled ds_write. Single-buffer m97 loop (r13 best-measured structure).
// grid (4,128,8) -> 4096 blocks, bijective XCD swizzle. 256 thr / 4 waves.
// ---------------------------------------------------------------------------
__global__ __launch_bounds__(256)
void gemm_s1f(const unsigned short* __restrict__ Wcat,
              const float* __restrict__ X, const float* __restrict__ H,
              unsigned short* __restrict__ Tcat)
{
    __shared__ alignas(16) unsigned short lds[16384];   // A 8192 | B 8192

    const int tid = threadIdx.x;
    const int lane = tid & 63;
    const int w = tid >> 6;

    int d = blockIdx.x + 4 * blockIdx.y + 512 * blockIdx.z;  // 0..4095
    int swz = (d & 7) * 512 + (d >> 3);                      // bijective (4096%8==0)
    const int x = swz & 3;
    const int b = (swz >> 2) & 127;
    const int gz = swz >> 9;
    const int g = gz >> 1, hf = gz & 1;
    const int tq = (x >> 1) * 128;     // A rows (q)
    const int ti = (x & 1) * 128;      // B rows (i)
    const int wm = (w >> 1) * 64;
    const int wn = (w & 1) * 64;

    const unsigned short* Ap = Wcat + (long)g * 131072 + (long)tq * 512 + hf * 256;
    const float* Bf = (hf ? H : X) + (long)b * 65536 + (long)ti * 256;

    f32x4 acc[4][4];
#pragma unroll
    for (int m = 0; m < 4; ++m)
#pragma unroll
        for (int n = 0; n < 4; ++n)
            acc[m][n] = (f32x4){0.f, 0.f, 0.f, 0.f};

    float4 pre[4][2];
    // prologue: preload B(0) fp32 into regs
#pragma unroll
    for (int it = 0; it < 4; ++it) {
        int li = it * 256 + tid;
        int row = li >> 3;
        int ck = li & 7;
        const float* ga = Bf + (long)row * 256 + ck * 8;
        pre[it][0] = *(const float4*)ga;
        pre[it][1] = *(const float4*)(ga + 4);
    }

#pragma unroll
    for (int t = 0; t < 4; ++t) {
        if (t > 0) __syncthreads();            // compute(t-1) done; lds reusable
        // A-tile via global_load_lds (async)
#pragma unroll
        for (int it = 0; it < 4; ++it) {
            int li = it * 256 + tid;
            int row = li >> 3;
            int sc = ((li & 7) ^ (row & 7)) * 8;
            __builtin_amdgcn_global_load_lds(
                (const __attribute__((address_space(1))) void*)(Ap + (long)row * 512 + t * 64 + sc),
                (__attribute__((address_space(3))) void*)&lds[li * 8], 16, 0, 0);
        }
        // B-tile: cvt preloaded fp32 -> bf16, swizzled ds_write
#pragma unroll
        for (int it = 0; it < 4; ++it) {
            int li = it * 256 + tid;
            int row = li >> 3;
            int ck = li & 7;
            const float* pf = (const float*)&pre[it][0];
            uint4 uv;
            uv.x = (unsigned)f2bf(pf[0]) | ((unsigned)f2bf(pf[1]) << 16);
            uv.y = (unsigned)f2bf(pf[2]) | ((unsigned)f2bf(pf[3]) << 16);
            uv.z = (unsigned)f2bf(pf[4]) | ((unsigned)f2bf(pf[5]) << 16);
            uv.w = (unsigned)f2bf(pf[6]) | ((unsigned)f2bf(pf[7]) << 16);
            *(uint4*)&lds[8192 + row * 64 + ((ck ^ (row & 7)) * 8)] = uv;
        }
        __syncthreads();                       // drains vmcnt (A) + lgkm (B writes)
        if (t < 3) {                           // prefetch next B under compute
#pragma unroll
            for (int it = 0; it < 4; ++it) {
                int li = it * 256 + tid;
                int row = li >> 3;
                int ck = li & 7;
                const float* ga = Bf + (long)row * 256 + (t + 1) * 64 + ck * 8;
                pre[it][0] = *(const float4*)ga;
                pre[it][1] = *(const float4*)(ga + 4);
            }
        }
        compute_tile(lds, lane, wm, wn, acc);  // acc[q_loc][i_loc]
    }

    unsigned short* Cb = Tcat + (long)g * 16777216 + (long)b * 131072 + hf * 256;
    const int r0 = (lane >> 4) * 4;
    const int c0 = lane & 15;
#pragma unroll
    for (int m = 0; m < 4; ++m)
#pragma unroll
        for (int n = 0; n < 4; ++n)
#pragma unroll
            for (int r = 0; r < 4; ++r) {
                int row = tq + wm + m * 16 + r0 + r;   // q
                int col = ti + wn + n * 16 + c0;       // i
                Cb[(long)row * 512 + col] = f2bf(acc[m][n][r]);
            }
}

// ---------------------------------------------------------------------------
// Stage 2, fused + balanced (r8/r13 form): one 128x128 (o,q) tile through all
// 4 gates (K=2048, 32 K-steps, dbuf pipeline). out_c = cell + relu(f)+relu(i)
// +relu(g) (fp32 + bf16 copy); out_h = relu(o). grid (4,128), 256 thr.
// ---------------------------------------------------------------------------
__global__ __launch_bounds__(256)
void gemm_gateB(const unsigned short* __restrict__ Tcat,
                const unsigned short* __restrict__ Wcat,
                const float* __restrict__ cell,
                float* __restrict__ out_c, float* __restrict__ out_h,
                unsigned short* __restrict__ cb16)
{
    __shared__ alignas(16) unsigned short lds[32768];   // 2 x (A|B)

    const int tid = threadIdx.x;
    const int lane = tid & 63;
    const int w = tid >> 6;

    int orig = blockIdx.x + 4 * blockIdx.y;              // 0..511
    int swz = (orig & 7) * 64 + (orig >> 3);             // XCD chunk swizzle
    const int x = swz & 3;
    const int b = swz >> 2;
    const int to = (x >> 1) * 128;     // A rows: Wcat o
    const int tq = (x & 1) * 128;      // B rows: S_T q
    const int wm = (w >> 1) * 64;
    const int wn = (w & 1) * 64;

    f32x4 accc[4][4], acc[4][4];
#pragma unroll
    for (int m = 0; m < 4; ++m)
#pragma unroll
        for (int n = 0; n < 4; ++n) {
            accc[m][n] = (f32x4){0.f, 0.f, 0.f, 0.f};
            acc[m][n] = (f32x4){0.f, 0.f, 0.f, 0.f};
        }

    // seg s processes gate gv = s ^ (s>>1): {0,1,3,2} = f,i,g,o (o last)
    {
        const unsigned short* Ap0 = Wcat + (long)to * 512;
        const unsigned short* Bp0 = Tcat + (long)b * 131072 + (long)tq * 512;
        stage_pair(Ap0, 512, Bp0, 512, lds, 0, tid);
    }
    for (int u = 0; u < 32; ++u) {
        __syncthreads();   // loads(u) landed; all waves done compute(u-1)
        if (u + 1 < 32) {
            int s = (u + 1) >> 3;
            int gv = s ^ (s >> 1);
            const unsigned short* Ap = Wcat + (long)gv * 131072 + (long)to * 512;
            const unsigned short* Bp = Tcat + (long)gv * 16777216 + (long)b * 131072 + (long)tq * 512;
            stage_pair(Ap, 512, Bp, 512, lds + ((u + 1) & 1) * 16384, ((u + 1) & 7) * 64, tid);
        }
        compute_tile(lds + (u & 1) * 16384, lane, wm, wn, acc);
        if ((u & 7) == 7 && u != 31) {   // fold f/i/g into accc
#pragma unroll
            for (int m = 0; m < 4; ++m)
#pragma unroll
                for (int n = 0; n < 4; ++n)
#pragma unroll
                    for (int r = 0; r < 4; ++r) {
                        float v = acc[m][n][r];
                        accc[m][n][r] += (v > 0.f ? v : 0.f);
                        acc[m][n][r] = 0.f;
                    }
        }
    }

    const float* cb = cell + (long)b * 65536;
    float* co = out_c + (long)b * 65536;
    float* ho = out_h + (long)b * 65536;
    unsigned short* cbo = cb16 + (long)b * 65536;
    const int r0 = (lane >> 4) * 4;
    const int c0 = lane & 15;
#pragma unroll
    for (int m = 0; m < 4; ++m)
#pragma unroll
        for (int n = 0; n < 4; ++n)
#pragma unroll
            for (int r = 0; r < 4; ++r) {
                int row = to + wm + m * 16 + r0 + r;   // o
                int col = tq + wn + n * 16 + c0;       // q
                long idx = (long)row * 256 + col;
                float cv = accc[m][n][r] + cb[idx];
                co[idx] = cv;
                cbo[idx] = f2bf(cv);
                float v = acc[m][n][r];                // o-gate
                ho[idx] = (v > 0.f ? v : 0.f);
            }
}

// ---------------------------------------------------------------------------
// Merged Woc chain (r13 form): per (q-tile, batch) block:
//   Phase A: Sc[q_loc][i] = bf16( sum_j Woc[q][j] * c[b][i][j] )  (LDS)
//   Phase B: out_h[b][o][tq+q_loc] += relu( sum_i Woc[o][i] * Sc[q_loc][i] )
// grid (2,128) = 256 blocks, 256 thr, 128KB LDS.
// ---------------------------------------------------------------------------
__global__ __launch_bounds__(256)
void gemm_woc(const unsigned short* __restrict__ Wocb,
              const unsigned short* __restrict__ cb16,
              float* __restrict__ out_h)
{
    __shared__ alignas(16) unsigned short stg[32768];   // 2 x (A 8192 | B 8192)
    __shared__ alignas(16) unsigned short Sc[32768];    // [128][256] swizzled bf16

    const int tid = threadIdx.x;
    const int lane = tid & 63;
    const int w = tid >> 6;

    int orig = blockIdx.x + 2 * blockIdx.y;              // 0..255
    int swz = (orig & 7) * 32 + (orig >> 3);             // bijective (256%8==0)
    const int b = swz >> 1;
    const int tq = (swz & 1) * 128;
    const int wm = (w >> 1) * 64;
    const int wn = (w & 1) * 64;
    const int r0 = (lane >> 4) * 4;
    const int c0 = lane & 15;

    // ---- Phase A: build Sc (q-tile x 256 i) ----
#pragma unroll
    for (int t2 = 0; t2 < 2; ++t2) {
        const unsigned short* Ap = Wocb + (long)tq * 256;
        const unsigned short* Bp = cb16 + (long)b * 65536 + (long)(t2 * 128) * 256;

        f32x4 acc[4][4];
#pragma unroll
        for (int m = 0; m < 4; ++m)
#pragma unroll
            for (int n = 0; n < 4; ++n)
                acc[m][n] = (f32x4){0.f, 0.f, 0.f, 0.f};

        stage_pair(Ap, 256, Bp, 256, stg, 0, tid);
#pragma unroll
        for (int t = 0; t < 4; ++t) {
            __syncthreads();
            if (t + 1 < 4)
                stage_pair(Ap, 256, Bp, 256, stg + ((t + 1) & 1) * 16384, (t + 1) * 64, tid);
            compute_tile(stg + (t & 1) * 16384, lane, wm, wn, acc);  // acc[q_loc][i_loc]
        }
        // write acc -> Sc bf16, swizzled (chunk-XOR within each 64-el group)
#pragma unroll
        for (int m = 0; m < 4; ++m)
#pragma unroll
            for (int n = 0; n < 4; ++n)
#pragma unroll
                for (int r = 0; r < 4; ++r) {
                    int qrow = wm + m * 16 + r0 + r;             // 0..127
                    int icol = t2 * 128 + wn + n * 16 + c0;      // 0..255
                    int addr = qrow * 256 + (icol & ~63)
                             + ((((icol >> 3) & 7) ^ (qrow & 7)) * 8) + (icol & 7);
                    Sc[addr] = f2bf(acc[m][n][r]);
                }
    }

    // ---- Phase B: out_h[o][tq+q] += relu( Woc[o,:] . Sc[q,:] ) ----
    float* ho = out_h + (long)b * 65536;
#pragma unroll
    for (int ot = 0; ot < 2; ++ot) {
        const unsigned short* Ap = Wocb + (long)(ot * 128) * 256;

        f32x4 acc[4][4];
#pragma unroll
        for (int m = 0; m < 4; ++m)
#pragma unroll
            for (int n = 0; n < 4; ++n)
                acc[m][n] = (f32x4){0.f, 0.f, 0.f, 0.f};

        stage_one(Ap, 256, stg, 0, tid);
#pragma unroll
        for (int t = 0; t < 4; ++t) {
            __syncthreads();   // first iter also fences Sc writes from phase A
            if (t + 1 < 4)
                stage_one(Ap, 256, stg + ((t + 1) & 1) * 16384, (t + 1) * 64, tid);
            compute_bsc(stg + (t & 1) * 16384, Sc, t * 64, lane, wm, wn, acc);
        }
#pragma unroll
        for (int m = 0; m < 4; ++m)
#pragma unroll
            for (int n = 0; n < 4; ++n)
#pragma unroll
                for (int r = 0; r < 4; ++r) {
                    int orow = ot * 128 + wm + m * 16 + r0 + r;
                    int qcol = tq + wn + n * 16 + c0;
                    long idx = (long)orow * 256 + qcol;
                    float v = acc[m][n][r];
                    ho[idx] += (v > 0.f ? v : 0.f);
                }
    }
}

// ---------------------------------------------------------------------------
extern "C" void kernel_launch(void* const* d_in, const int* in_sizes, int n_in,
                              void* d_out, int out_size, void* d_ws, size_t ws_size,
                              hipStream_t stream)
{
    (void)in_sizes; (void)n_in; (void)out_size; (void)ws_size;

    const float* X    = (const float*)d_in[0];
    const float* H    = (const float*)d_in[1];
    const float* cell = (const float*)d_in[2];
    const float* Wxp[4] = {(const float*)d_in[3], (const float*)d_in[4],
                           (const float*)d_in[5], (const float*)d_in[6]};
    const float* Whp[4] = {(const float*)d_in[7], (const float*)d_in[8],
                           (const float*)d_in[9], (const float*)d_in[10]};
    const float* Wocf = (const float*)d_in[11];

    float* out_h = (float*)d_out;                  // [128][256][256]
    float* out_c = out_h + 8388608;                // [128][256][256]

    unsigned short* ws   = (unsigned short*)d_ws;  // bf16 elements (ws = 256 MiB)
    unsigned short* Wcat = ws;                     //    524,288 el [4][256][512]
    unsigned short* Wocb = ws + 524288;            //     65,536 el
    unsigned short* Tcat = ws + 589824;            // 67,108,864 el [4][128][256][512]
    unsigned short* cb16 = ws + 67698688;          //  8,388,608 el (c bf16, natural)

    // 1. weights -> bf16 (tiny)
    cvt_w<<<dim3(2304), 256, 0, stream>>>(Wxp[0], Wxp[1], Wxp[2], Wxp[3],
                                          Whp[0], Whp[1], Whp[2], Whp[3],
                                          Wocf, Wcat, Wocb);
    // 2. stage 1 all gates, fused fp32 consume: S_T[g][b][q][i']
    gemm_s1f<<<dim3(4, 128, 8), 256, 0, stream>>>(Wcat, X, H, Tcat);
    // 3. stage 2 fused+balanced: all 4 gates -> out_c (+bf16 copy), out_h
    gemm_gateB<<<dim3(4, 128), 256, 0, stream>>>(Tcat, Wcat, cell, out_c, out_h, cb16);
    // 4. merged Woc chain: Sc in LDS, h = ogate + relu(Woc . (Woc . c^T)^T)
    gemm_woc<<<dim3(2, 128), 256, 0, stream>>>(Wocb, cb16, out_h);
}

// Round 15
// 171.238 us; speedup vs baseline: 1.2609x; 1.2609x over previous
//
#include <hip/hip_runtime.h>

typedef __bf16 bf16x8 __attribute__((ext_vector_type(8)));
typedef float f32x4 __attribute__((ext_vector_type(4)));

__device__ __forceinline__ unsigned short f2bf(float f) {
    unsigned int u = __builtin_bit_cast(unsigned int, f);
    u += 0x7fff + ((u >> 16) & 1);   // round-to-nearest-even (finite inputs)
    return (unsigned short)(u >> 16);
}

// ---------------------------------------------------------------------------
// Stage a 128x64 A-tile + 128x64 B-tile (bf16) into lds[0..8191]/[8192..16383]
// via global_load_lds. Source chunk pre-swizzled c^(row&7); read side applies
// the same XOR (both-sides-or-neither, rule #21). 256 threads x 4 iters.
// ---------------------------------------------------------------------------
__device__ __forceinline__ void stage_pair(
    const unsigned short* __restrict__ Ap, int lda,
    const unsigned short* __restrict__ Bp, int ldb,
    unsigned short* lds, int k0, int tid)
{
#pragma unroll
    for (int it = 0; it < 4; ++it) {
        int li = it * 256 + tid;          // 0..1023: row = li>>3, chunk = li&7
        int row = li >> 3;
        int sc = ((li & 7) ^ (row & 7)) * 8;
        __builtin_amdgcn_global_load_lds(
            (const __attribute__((address_space(1))) void*)(Ap + (long)row * lda + k0 + sc),
            (__attribute__((address_space(3))) void*)&lds[li * 8], 16, 0, 0);
        __builtin_amdgcn_global_load_lds(
            (const __attribute__((address_space(1))) void*)(Bp + (long)row * ldb + k0 + sc),
            (__attribute__((address_space(3))) void*)&lds[8192 + li * 8], 16, 0, 0);
    }
}

// Stage just one 128x64 A-tile (8192 el) into buf.
__device__ __forceinline__ void stage_one(
    const unsigned short* __restrict__ Ap, int lda,
    unsigned short* buf, int k0, int tid)
{
#pragma unroll
    for (int it = 0; it < 4; ++it) {
        int li = it * 256 + tid;
        int row = li >> 3;
        int sc = ((li & 7) ^ (row & 7)) * 8;
        __builtin_amdgcn_global_load_lds(
            (const __attribute__((address_space(1))) void*)(Ap + (long)row * lda + k0 + sc),
            (__attribute__((address_space(3))) void*)&buf[li * 8], 16, 0, 0);
    }
}

// ---------------------------------------------------------------------------
// One 64-deep K-step from a staged tile pair (swizzled read).
// 4 waves, wave-tile 64x64, acc[4][4]. D row <- A-tile row, D col <- B row.
// ---------------------------------------------------------------------------
__device__ __forceinline__ void compute_tile(
    const unsigned short* lds, int lane, int wm, int wn, f32x4 (&acc)[4][4])
{
#pragma unroll
    for (int kk = 0; kk < 2; ++kk) {
        const int cl = kk * 4 + (lane >> 4);
        bf16x8 af[4], bfr[4];
#pragma unroll
        for (int m = 0; m < 4; ++m) {
            int row = wm + m * 16 + (lane & 15);
            af[m] = *(const bf16x8*)&lds[row * 64 + ((cl ^ (row & 7)) * 8)];
        }
#pragma unroll
        for (int n = 0; n < 4; ++n) {
            int row = wn + n * 16 + (lane & 15);
            bfr[n] = *(const bf16x8*)&lds[8192 + row * 64 + ((cl ^ (row & 7)) * 8)];
        }
#pragma unroll
        for (int m = 0; m < 4; ++m)
#pragma unroll
            for (int n = 0; n < 4; ++n)
                acc[m][n] = __builtin_amdgcn_mfma_f32_16x16x32_bf16(af[m], bfr[n], acc[m][n], 0, 0, 0);
    }
}

// Like compute_tile but B-fragments come from a [128][256] swizzled LDS Sc
// buffer at K-offset k0 (A from a staged 128x64 buffer).
__device__ __forceinline__ void compute_bsc(
    const unsigned short* bufA, const unsigned short* Sc, int k0,
    int lane, int wm, int wn, f32x4 (&acc)[4][4])
{
#pragma unroll
    for (int kk = 0; kk < 2; ++kk) {
        const int cl = kk * 4 + (lane >> 4);
        bf16x8 af[4], bfr[4];
#pragma unroll
        for (int m = 0; m < 4; ++m) {
            int row = wm + m * 16 + (lane & 15);
            af[m] = *(const bf16x8*)&bufA[row * 64 + ((cl ^ (row & 7)) * 8)];
        }
#pragma unroll
        for (int n = 0; n < 4; ++n) {
            int row = wn + n * 16 + (lane & 15);
            bfr[n] = *(const bf16x8*)&Sc[row * 256 + k0 + ((cl ^ (row & 7)) * 8)];
        }
#pragma unroll
        for (int m = 0; m < 4; ++m)
#pragma unroll
            for (int n = 0; n < 4; ++n)
                acc[m][n] = __builtin_amdgcn_mfma_f32_16x16x32_bf16(af[m], bfr[n], acc[m][n], 0, 0, 0);
    }
}

// Barriers for the counted-vmcnt pipeline (T4): never drain to 0 mid-loop.
__device__ __forceinline__ void midbar() {
    __builtin_amdgcn_sched_barrier(0);
    __builtin_amdgcn_s_barrier();
    __builtin_amdgcn_sched_barrier(0);
}
__device__ __forceinline__ void endbar6() {
    asm volatile("s_waitcnt vmcnt(6)" ::: "memory");
    __builtin_amdgcn_sched_barrier(0);
    __builtin_amdgcn_s_barrier();
    __builtin_amdgcn_sched_barrier(0);
}
__device__ __forceinline__ void endbar0() {
    asm volatile("s_waitcnt vmcnt(0)" ::: "memory");
    __builtin_amdgcn_sched_barrier(0);
    __builtin_amdgcn_s_barrier();
    __builtin_amdgcn_sched_barrier(0);
}

// ---------------------------------------------------------------------------
// Fused conversions: blocks [0,8192): X,H fp32->bf16 streaming;
// blocks [8192,10496): Wcat[g][q][512]=[Wgx|Wgh] bf16 + Woc bf16.
// ---------------------------------------------------------------------------
__global__ __launch_bounds__(256)
void cvt_all(const float* __restrict__ X, const float* __restrict__ H,
             unsigned short* __restrict__ XHb,
             const float* __restrict__ fx, const float* __restrict__ ix,
             const float* __restrict__ ox, const float* __restrict__ gx,
             const float* __restrict__ fh, const float* __restrict__ ih,
             const float* __restrict__ oh, const float* __restrict__ gh,
             const float* __restrict__ oc,
             unsigned short* __restrict__ Wcat, unsigned short* __restrict__ Wocb)
{
    int bid = blockIdx.x;
    if (bid < 8192) {
        long e = ((long)bid * 256 + threadIdx.x) * 8;
        const float* s = (e < 8388608) ? (X + e) : (H + (e - 8388608));
        float4 a = *(const float4*)s;
        float4 c = *(const float4*)(s + 4);
        uint4 uv;
        uv.x = (unsigned)f2bf(a.x) | ((unsigned)f2bf(a.y) << 16);
        uv.y = (unsigned)f2bf(a.z) | ((unsigned)f2bf(a.w) << 16);
        uv.z = (unsigned)f2bf(c.x) | ((unsigned)f2bf(c.y) << 16);
        uv.w = (unsigned)f2bf(c.z) | ((unsigned)f2bf(c.w) << 16);
        *(uint4*)&XHb[e] = uv;
    } else {
        int idx = (bid - 8192) * 256 + threadIdx.x;
        if (idx < 524288) {
            int g = idx >> 17;
            int rem = idx & 131071;
            int q = rem >> 9;
            int j = rem & 511;
            const float* xs = (g == 0) ? fx : (g == 1) ? ix : (g == 2) ? ox : gx;
            const float* hs = (g == 0) ? fh : (g == 1) ? ih : (g == 2) ? oh : gh;
            float v = (j < 256) ? xs[q * 256 + j] : hs[q * 256 + (j - 256)];
            Wcat[idx] = f2bf(v);
        } else if (idx < 589824) {
            int k = idx - 524288;
            Wocb[k] = f2bf(oc[k]);
        }
    }
}

// ---------------------------------------------------------------------------
// Stage 1, flipped NT (r13 best-measured form), single-buffered m97 loop:
//   S_T[g][b][q][hf*256+i] = sum_j Wcat[g][q][hf*256+j] * M_hf[b][i][j]
// grid (4,128,8) -> 4096 blocks, bijective XCD swizzle. 256 thr / 4 waves.
// ---------------------------------------------------------------------------
__global__ __launch_bounds__(256)
void gemm_s1(const unsigned short* __restrict__ Wcat,
             const unsigned short* __restrict__ XHb,
             unsigned short* __restrict__ Tcat)
{
    __shared__ alignas(16) unsigned short lds[16384];   // A 8192 | B 8192

    const int tid = threadIdx.x;
    const int lane = tid & 63;
    const int w = tid >> 6;

    int d = blockIdx.x + 4 * blockIdx.y + 512 * blockIdx.z;  // 0..4095
    int swz = (d & 7) * 512 + (d >> 3);                      // bijective (4096%8==0)
    const int x = swz & 3;
    const int b = (swz >> 2) & 127;
    const int gz = swz >> 9;
    const int g = gz >> 1, hf = gz & 1;
    const int tq = (x >> 1) * 128;     // A rows (q)
    const int ti = (x & 1) * 128;      // B rows (i)
    const int wm = (w >> 1) * 64;
    const int wn = (w & 1) * 64;

    const unsigned short* Ap = Wcat + (long)g * 131072 + (long)tq * 512 + hf * 256;
    const unsigned short* Bp = XHb + (long)hf * 8388608 + (long)b * 65536 + (long)ti * 256;

    f32x4 acc[4][4];
#pragma unroll
    for (int m = 0; m < 4; ++m)
#pragma unroll
        for (int n = 0; n < 4; ++n)
            acc[m][n] = (f32x4){0.f, 0.f, 0.f, 0.f};

#pragma unroll
    for (int t = 0; t < 4; ++t) {
        if (t > 0) __syncthreads();
        stage_pair(Ap, 512, Bp, 256, lds, t * 64, tid);
        __syncthreads();
        compute_tile(lds, lane, wm, wn, acc);   // acc[q_loc][i_loc]
    }

    unsigned short* Cb = Tcat + (long)g * 16777216 + (long)b * 131072 + hf * 256;
    const int r0 = (lane >> 4) * 4;
    const int c0 = lane & 15;
#pragma unroll
    for (int m = 0; m < 4; ++m)
#pragma unroll
        for (int n = 0; n < 4; ++n)
#pragma unroll
            for (int r = 0; r < 4; ++r) {
                int row = tq + wm + m * 16 + r0 + r;   // q
                int col = ti + wn + n * 16 + c0;       // i
                Cb[(long)row * 512 + col] = f2bf(acc[m][n][r]);
            }
}

// ---------------------------------------------------------------------------
// Stage 2, 8-phase-style counted-vmcnt pipeline (T3+T4+T5):
// BM=128 (o-half) x BN=256 (all q of one batch), 512 thr / 8 waves (2x4),
// wave-tile 64x64. K = 4 gates x 512 = 32 steps of 64. 3 staging buffers
// (48KB each, 144KB LDS), prefetch depth 2, vmcnt(6) at step end (never 0
// until epilogue). Per step: 2 phases, each {stage-chunk, 16-MFMA cluster
// (setprio), barrier}. out_c = cell + relu(f)+relu(i)+relu(g) (+bf16 copy);
// out_h = relu(o). grid (2,128) = 256 blocks (1/CU).
// Buffer safety: buf[(u+2)%3] staged at step u was last read at step u-1;
// writes issue only after u-1's end barrier -> race-free.
// ---------------------------------------------------------------------------
__global__ __launch_bounds__(512)
void gemm_gateB8(const unsigned short* __restrict__ Tcat,
                 const unsigned short* __restrict__ Wcat,
                 const float* __restrict__ cell,
                 float* __restrict__ out_c, float* __restrict__ out_h,
                 unsigned short* __restrict__ cb16)
{
    __shared__ alignas(16) unsigned short lds[73728];   // 3 x (A 8192 | B 16384)

    const int tid = threadIdx.x;
    const int lane = tid & 63;
    const int w = tid >> 6;            // 0..7

    int orig = blockIdx.x + 2 * blockIdx.y;              // 0..255
    int swz = (orig & 7) * 32 + (orig >> 3);             // bijective; the two
    const int b = swz >> 1;                              // o-halves of a batch
    const int to = (swz & 1) * 128;                      // land on one XCD
    const int wm = (w >> 2) * 64;      // o offset in 128
    const int wn = (w & 3) * 64;       // q offset in 256

    const unsigned short* Ab = Wcat + (long)to * 512;    // + gv*131072
    const unsigned short* Bb = Tcat + (long)b * 131072;  // + gv*16777216

    f32x4 accc[4][4], acc[4][4];
#pragma unroll
    for (int m = 0; m < 4; ++m)
#pragma unroll
        for (int n = 0; n < 4; ++n) {
            accc[m][n] = (f32x4){0.f, 0.f, 0.f, 0.f};
            acc[m][n] = (f32x4){0.f, 0.f, 0.f, 0.f};
        }

    // stage helper: part 0 = A(2 loads)+B chunk0(1); part 1 = B chunks 1-3.
    auto stage = [&](int u, int part) {
        int s = u >> 3;
        int gv = s ^ (s >> 1);                 // {0,1,3,2} = f,i,g,o
        int k0 = (u & 7) * 64;
        const unsigned short* Ap = Ab + (long)gv * 131072;
        const unsigned short* Bp = Bb + (long)gv * 16777216;
        unsigned short* buf = lds + (u % 3) * 24576;
        if (part == 0) {
#pragma unroll
            for (int it = 0; it < 2; ++it) {
                int li = it * 512 + tid;       // A: 0..1023
                int row = li >> 3;
                int sc = ((li & 7) ^ (row & 7)) * 8;
                __builtin_amdgcn_global_load_lds(
                    (const __attribute__((address_space(1))) void*)(Ap + (long)row * 512 + k0 + sc),
                    (__attribute__((address_space(3))) void*)&buf[li * 8], 16, 0, 0);
            }
            {
                int li = tid;                  // B it=0: 0..511
                int row = li >> 3;
                int sc = ((li & 7) ^ (row & 7)) * 8;
                __builtin_amdgcn_global_load_lds(
                    (const __attribute__((address_space(1))) void*)(Bp + (long)row * 512 + k0 + sc),
                    (__attribute__((address_space(3))) void*)&buf[8192 + li * 8], 16, 0, 0);
            }
        } else {
#pragma unroll
            for (int it = 1; it < 4; ++it) {
                int li = it * 512 + tid;       // B: 512..2047
                int row = li >> 3;
                int sc = ((li & 7) ^ (row & 7)) * 8;
                __builtin_amdgcn_global_load_lds(
                    (const __attribute__((address_space(1))) void*)(Bp + (long)row * 512 + k0 + sc),
                    (__attribute__((address_space(3))) void*)&buf[8192 + li * 8], 16, 0, 0);
            }
        }
    };

    // one kk-half: 8 ds_read + 16 MFMA (setprio-wrapped cluster)
    auto chalf = [&](const unsigned short* buf, int kk) {
        const int cl = kk * 4 + (lane >> 4);
        bf16x8 af[4], bfr[4];
#pragma unroll
        for (int m = 0; m < 4; ++m) {
            int row = wm + m * 16 + (lane & 15);
            af[m] = *(const bf16x8*)&buf[row * 64 + ((cl ^ (row & 7)) * 8)];
        }
#pragma unroll
        for (int n = 0; n < 4; ++n) {
            int row = wn + n * 16 + (lane & 15);
            bfr[n] = *(const bf16x8*)&buf[8192 + row * 64 + ((cl ^ (row & 7)) * 8)];
        }
        __builtin_amdgcn_s_setprio(1);
#pragma unroll
        for (int m = 0; m < 4; ++m)
#pragma unroll
            for (int n = 0; n < 4; ++n)
                acc[m][n] = __builtin_amdgcn_mfma_f32_16x16x32_bf16(af[m], bfr[n], acc[m][n], 0, 0, 0);
        __builtin_amdgcn_s_setprio(0);
    };

    // prologue: fully stage steps 0 and 1; ensure step 0 landed.
    stage(0, 0); stage(0, 1);
    stage(1, 0); stage(1, 1);
    endbar6();

    for (int u = 0; u < 32; ++u) {
        const unsigned short* cur = lds + (u % 3) * 24576;
        // phase A
        if (u + 2 < 32) stage(u + 2, 0);
        chalf(cur, 0);
        midbar();
        // phase B
        if (u + 2 < 32) stage(u + 2, 1);
        chalf(cur, 1);
        if ((u & 7) == 7 && u != 31) {         // fold f/i/g into accc
#pragma unroll
            for (int m = 0; m < 4; ++m)
#pragma unroll
                for (int n = 0; n < 4; ++n)
#pragma unroll
                    for (int r = 0; r < 4; ++r) {
                        float v = acc[m][n][r];
                        accc[m][n][r] += (v > 0.f ? v : 0.f);
                        acc[m][n][r] = 0.f;
                    }
        }
        if (u < 30) endbar6(); else endbar0();
    }

    const float* cb = cell + (long)b * 65536;
    float* co = out_c + (long)b * 65536;
    float* ho = out_h + (long)b * 65536;
    unsigned short* cbo = cb16 + (long)b * 65536;
    const int r0 = (lane >> 4) * 4;
    const int c0 = lane & 15;
#pragma unroll
    for (int m = 0; m < 4; ++m)
#pragma unroll
        for (int n = 0; n < 4; ++n)
#pragma unroll
            for (int r = 0; r < 4; ++r) {
                int row = to + wm + m * 16 + r0 + r;   // o
                int col = wn + n * 16 + c0;            // q (0..255)
                long idx = (long)row * 256 + col;
                float cv = accc[m][n][r] + cb[idx];
                co[idx] = cv;
                cbo[idx] = f2bf(cv);
                float v = acc[m][n][r];                // o-gate
                ho[idx] = (v > 0.f ? v : 0.f);
            }
}

// ---------------------------------------------------------------------------
// Merged Woc chain (r13 form): per (q-tile, batch) block:
//   Phase A: Sc[q_loc][i] = bf16( sum_j Woc[q][j] * c[b][i][j] )  (LDS)
//   Phase B: out_h[b][o][tq+q_loc] += relu( sum_i Woc[o][i] * Sc[q_loc][i] )
// grid (2,128) = 256 blocks, 256 thr, 128KB LDS.
// ---------------------------------------------------------------------------
__global__ __launch_bounds__(256)
void gemm_woc(const unsigned short* __restrict__ Wocb,
              const unsigned short* __restrict__ cb16,
              float* __restrict__ out_h)
{
    __shared__ alignas(16) unsigned short stg[32768];   // 2 x (A 8192 | B 8192)
    __shared__ alignas(16) unsigned short Sc[32768];    // [128][256] swizzled bf16

    const int tid = threadIdx.x;
    const int lane = tid & 63;
    const int w = tid >> 6;

    int orig = blockIdx.x + 2 * blockIdx.y;              // 0..255
    int swz = (orig & 7) * 32 + (orig >> 3);             // bijective (256%8==0)
    const int b = swz >> 1;
    const int tq = (swz & 1) * 128;
    const int wm = (w >> 1) * 64;
    const int wn = (w & 1) * 64;
    const int r0 = (lane >> 4) * 4;
    const int c0 = lane & 15;

    // ---- Phase A: build Sc (q-tile x 256 i) ----
#pragma unroll
    for (int t2 = 0; t2 < 2; ++t2) {
        const unsigned short* Ap = Wocb + (long)tq * 256;
        const unsigned short* Bp = cb16 + (long)b * 65536 + (long)(t2 * 128) * 256;

        f32x4 acc[4][4];
#pragma unroll
        for (int m = 0; m < 4; ++m)
#pragma unroll
            for (int n = 0; n < 4; ++n)
                acc[m][n] = (f32x4){0.f, 0.f, 0.f, 0.f};

        stage_pair(Ap, 256, Bp, 256, stg, 0, tid);
#pragma unroll
        for (int t = 0; t < 4; ++t) {
            __syncthreads();
            if (t + 1 < 4)
                stage_pair(Ap, 256, Bp, 256, stg + ((t + 1) & 1) * 16384, (t + 1) * 64, tid);
            compute_tile(stg + (t & 1) * 16384, lane, wm, wn, acc);  // acc[q_loc][i_loc]
        }
        // write acc -> Sc bf16, swizzled (chunk-XOR within each 64-el group)
#pragma unroll
        for (int m = 0; m < 4; ++m)
#pragma unroll
            for (int n = 0; n < 4; ++n)
#pragma unroll
                for (int r = 0; r < 4; ++r) {
                    int qrow = wm + m * 16 + r0 + r;             // 0..127
                    int icol = t2 * 128 + wn + n * 16 + c0;      // 0..255
                    int addr = qrow * 256 + (icol & ~63)
                             + ((((icol >> 3) & 7) ^ (qrow & 7)) * 8) + (icol & 7);
                    Sc[addr] = f2bf(acc[m][n][r]);
                }
    }

    // ---- Phase B: out_h[o][tq+q] += relu( Woc[o,:] . Sc[q,:] ) ----
    float* ho = out_h + (long)b * 65536;
#pragma unroll
    for (int ot = 0; ot < 2; ++ot) {
        const unsigned short* Ap = Wocb + (long)(ot * 128) * 256;

        f32x4 acc[4][4];
#pragma unroll
        for (int m = 0; m < 4; ++m)
#pragma unroll
            for (int n = 0; n < 4; ++n)
                acc[m][n] = (f32x4){0.f, 0.f, 0.f, 0.f};

        stage_one(Ap, 256, stg, 0, tid);
#pragma unroll
        for (int t = 0; t < 4; ++t) {
            __syncthreads();   // first iter also fences Sc writes from phase A
            if (t + 1 < 4)
                stage_one(Ap, 256, stg + ((t + 1) & 1) * 16384, (t + 1) * 64, tid);
            compute_bsc(stg + (t & 1) * 16384, Sc, t * 64, lane, wm, wn, acc);
        }
#pragma unroll
        for (int m = 0; m < 4; ++m)
#pragma unroll
            for (int n = 0; n < 4; ++n)
#pragma unroll
                for (int r = 0; r < 4; ++r) {
                    int orow = ot * 128 + wm + m * 16 + r0 + r;
                    int qcol = tq + wn + n * 16 + c0;
                    long idx = (long)orow * 256 + qcol;
                    float v = acc[m][n][r];
                    ho[idx] += (v > 0.f ? v : 0.f);
                }
    }
}

// ---------------------------------------------------------------------------
extern "C" void kernel_launch(void* const* d_in, const int* in_sizes, int n_in,
                              void* d_out, int out_size, void* d_ws, size_t ws_size,
                              hipStream_t stream)
{
    (void)in_sizes; (void)n_in; (void)out_size; (void)ws_size;

    const float* X    = (const float*)d_in[0];
    const float* H    = (const float*)d_in[1];
    const float* cell = (const float*)d_in[2];
    const float* Wxp[4] = {(const float*)d_in[3], (const float*)d_in[4],
                           (const float*)d_in[5], (const float*)d_in[6]};
    const float* Whp[4] = {(const float*)d_in[7], (const float*)d_in[8],
                           (const float*)d_in[9], (const float*)d_in[10]};
    const float* Wocf = (const float*)d_in[11];

    float* out_h = (float*)d_out;                  // [128][256][256]
    float* out_c = out_h + 8388608;                // [128][256][256]

    unsigned short* ws   = (unsigned short*)d_ws;  // bf16 elements (ws = 256 MiB)
    unsigned short* XHb  = ws;                     // 16,777,216 el [2][128][256][256]
    unsigned short* Wcat = ws + 16777216;          //    524,288 el [4][256][512]
    unsigned short* Wocb = ws + 17301504;          //     65,536 el
    unsigned short* Tcat = ws + 17367040;          // 67,108,864 el [4][128][256][512]
    unsigned short* cb16 = ws + 84475904;          //  8,388,608 el (c bf16, natural)

    // 1. all conversions (X,H streaming + weights)
    cvt_all<<<dim3(10496), 256, 0, stream>>>(X, H, XHb,
                                             Wxp[0], Wxp[1], Wxp[2], Wxp[3],
                                             Whp[0], Whp[1], Whp[2], Whp[3],
                                             Wocf, Wcat, Wocb);
    // 2. stage 1 all gates, flipped NT: S_T[g][b][q][i']
    gemm_s1<<<dim3(4, 128, 8), 256, 0, stream>>>(Wcat, XHb, Tcat);
    // 3. stage 2, 8-phase counted-vmcnt: all 4 gates -> out_c (+bf16), out_h
    gemm_gateB8<<<dim3(2, 128), 512, 0, stream>>>(Tcat, Wcat, cell, out_c, out_h, cb16);
    // 4. merged Woc chain: Sc in LDS, h = ogate + relu(Woc . (Woc . c^T)^T)
    gemm_woc<<<dim3(2, 128), 256, 0, stream>>>(Wocb, cb16, out_h);
}